// Round 16
// baseline (666.550 us; speedup 1.0000x reference)
//
#include <hip/hip_runtime.h>
#include <hip/hip_bf16.h>

#define DEVINL __device__ __forceinline__

constexpr int Cc  = 256;
constexpr int Hh  = 56;
constexpr int Ww  = 56;
constexpr int Tn  = 32 * 56 * 56;   // 100352 tokens
constexpr int HW  = Hh * Ww;        // 3136
constexpr float SCALEF = 0.17677669529663689f;  // 32^-0.5

typedef __attribute__((ext_vector_type(4))) float f32x4;
typedef __attribute__((ext_vector_type(8))) short bf16x8;

DEVINL unsigned short f2bf(float f) {
  __hip_bfloat16 h = __float2bfloat16(f);
  return *reinterpret_cast<unsigned short*>(&h);
}
DEVINL float bf2f(unsigned short u) {
  union { unsigned int i; float f; } v; v.i = (unsigned int)u << 16; return v.f;
}

#define GLOAD_LDS16(gp, lp) \
  __builtin_amdgcn_global_load_lds((const __attribute__((address_space(1))) void*)(gp), \
                                   (__attribute__((address_space(3))) void*)(lp), 16, 0, 0)

// ------------- Kernel 1: depthwise 3x3 CPE + residual -> token(t,c) bf16 --------
// LDS strides 620(ch)/60(row): 8B-aligned rows -> ushort4+ushort2 vector reads.
__global__ __launch_bounds__(256) void cpe_kernel(const float* __restrict__ x,
    const float* __restrict__ cw, const float* __restrict__ cb,
    unsigned short* __restrict__ out)
{
  __shared__ unsigned short Xs[16 * 620];
  const int tid = threadIdx.x;
  const int bx  = blockIdx.x;
  const int cg  = bx & 15;
  const int t2  = bx >> 4;
  const int hg  = t2 % 7;
  const int b   = t2 / 7;
  const int c0  = cg * 16;
  const int h0  = hg * 8;

  for (int idx = tid; idx < 16 * 580; idx += 256) {
    const int ci  = idx / 580;
    const int rem = idx - ci * 580;
    const int rr  = rem / 58;
    const int wc  = rem - rr * 58;
    const int h2  = h0 - 1 + rr;
    const int w2  = wc - 1;
    float v = 0.f;
    if (h2 >= 0 && h2 < Hh && w2 >= 0 && w2 < Ww)
      v = x[((size_t)(b * Cc + c0 + ci)) * HW + h2 * Ww + w2];
    Xs[ci * 620 + rr * 60 + wc] = f2bf(v);
  }
  __syncthreads();

  const int ci = tid & 15;
  const int c  = c0 + ci;
  float wr9[9];
  #pragma unroll
  for (int i = 0; i < 9; ++i) wr9[i] = cw[c * 9 + i];
  const float cbv = cb[c];
  const unsigned short* Xc = Xs + ci * 620;

  #pragma unroll
  for (int it = 0; it < 7; ++it) {
    const int tg   = it * 16 + (tid >> 4);
    const int tok0 = tg * 4;
    const int hr   = tok0 / 56;
    const int w0   = tok0 - hr * 56;
    float rv[3][6];
    #pragma unroll
    for (int j = 0; j < 3; ++j) {
      const ushort4 a = *reinterpret_cast<const ushort4*>(Xc + (hr + j) * 60 + w0);
      const ushort2 e = *reinterpret_cast<const ushort2*>(Xc + (hr + j) * 60 + w0 + 4);
      rv[j][0] = bf2f(a.x); rv[j][1] = bf2f(a.y); rv[j][2] = bf2f(a.z);
      rv[j][3] = bf2f(a.w); rv[j][4] = bf2f(e.x); rv[j][5] = bf2f(e.y);
    }
    unsigned short ov[4];
    #pragma unroll
    for (int t = 0; t < 4; ++t) {
      float acc = rv[1][t + 1];   // residual (center x)
      acc += wr9[0] * rv[0][t] + wr9[1] * rv[0][t + 1] + wr9[2] * rv[0][t + 2];
      acc += wr9[3] * rv[1][t] + wr9[4] * rv[1][t + 1] + wr9[5] * rv[1][t + 2];
      acc += wr9[6] * rv[2][t] + wr9[7] * rv[2][t + 1] + wr9[8] * rv[2][t + 2];
      ov[t] = f2bf(acc + cbv);
    }
    const size_t tbase = (size_t)b * HW + (h0 + hr) * Ww + w0;
    #pragma unroll
    for (int t = 0; t < 4; ++t)
      out[(tbase + t) * Cc + c] = ov[t];
  }
}

// ------------- Kernel 2: per-token LN stats on bf16 rows -> float2{mu, rs} ------
__global__ __launch_bounds__(256) void stats_bf16(const unsigned short* __restrict__ in,
    float2* __restrict__ st)
{
  const int lane = threadIdx.x & 63;
  const size_t t = (size_t)blockIdx.x * 4 + (threadIdx.x >> 6);
  const ushort4 v = *reinterpret_cast<const ushort4*>(in + t * Cc + lane * 4);
  const float v0 = bf2f(v.x), v1 = bf2f(v.y), v2 = bf2f(v.z), v3 = bf2f(v.w);
  float s  = v0 + v1 + v2 + v3;
  float sq = v0 * v0 + v1 * v1 + v2 * v2 + v3 * v3;
  #pragma unroll
  for (int o = 32; o >= 1; o >>= 1) {
    s  += __shfl_xor(s, o);
    sq += __shfl_xor(sq, o);
  }
  if (lane == 0) {
    const float mean = s * (1.0f / Cc);
    const float var  = sq * (1.0f / Cc) - mean * mean;
    st[t] = make_float2(mean, rsqrtf(var + 1e-5f));
  }
}

// ------------- Kernel 2b: fused LN stats+apply, bf16 -> bf16 --------------------
__global__ __launch_bounds__(256) void ln_apply_bf16(const unsigned short* __restrict__ inp,
    const float* __restrict__ w, const float* __restrict__ b,
    unsigned short* __restrict__ out)
{
  const int lane = threadIdx.x & 63;
  const size_t t = (size_t)blockIdx.x * 4 + (threadIdx.x >> 6);
  const ushort4 v = *reinterpret_cast<const ushort4*>(inp + t * Cc + lane * 4);
  const float v0 = bf2f(v.x), v1 = bf2f(v.y), v2 = bf2f(v.z), v3 = bf2f(v.w);
  float s  = v0 + v1 + v2 + v3;
  float sq = v0 * v0 + v1 * v1 + v2 * v2 + v3 * v3;
  #pragma unroll
  for (int o = 32; o >= 1; o >>= 1) {
    s  += __shfl_xor(s, o);
    sq += __shfl_xor(sq, o);
  }
  const float mean = s * (1.0f / Cc);
  const float var  = sq * (1.0f / Cc) - mean * mean;
  const float r    = rsqrtf(var + 1e-5f);
  const float4 w4 = *reinterpret_cast<const float4*>(w + lane * 4);
  const float4 b4 = *reinterpret_cast<const float4*>(b + lane * 4);
  ushort4 o;
  o.x = f2bf((v0 - mean) * r * w4.x + b4.x);
  o.y = f2bf((v1 - mean) * r * w4.y + b4.y);
  o.z = f2bf((v2 - mean) * r * w4.z + b4.z);
  o.w = f2bf((v3 - mean) * r * w4.w + b4.w);
  *reinterpret_cast<ushort4*>(out + t * Cc + lane * 4) = o;
}

// ------------- Kernel 3: weight transpose+fold f32[K][N] -> bf16 Wt[N][K] -------
template<int QS>
__global__ __launch_bounds__(256) void wconv_kernel(const float* __restrict__ W,
    const float* __restrict__ g, unsigned short* __restrict__ Wt, int K, int N)
{
  __shared__ float Xs[32][33];
  const int kb = blockIdx.x * 32, nb = blockIdx.y * 32;
  const int tn = threadIdx.x & 31, tk = threadIdx.x >> 5;
  #pragma unroll
  for (int i = 0; i < 4; ++i) {
    const int k = kb + tk + i * 8;
    const float gv = g ? g[k] : 1.0f;
    Xs[tk + i * 8][tn] = W[(size_t)k * N + nb + tn] * gv;
  }
  __syncthreads();
  const int wk = threadIdx.x & 31, wn = threadIdx.x >> 5;
  #pragma unroll
  for (int i = 0; i < 4; ++i) {
    const int n = nb + wn + i * 8;
    const float s = (QS && n < 256) ? SCALEF : 1.0f;
    Wt[(size_t)n * K + kb + wk] = f2bf(Xs[wk][wn + i * 8] * s);
  }
}

// ------------- Kernel 3b: C1[n]=s*sum_k g_k W,  CB[n]=s*(sum_k b_k W + bias) ----
template<int S>
__global__ __launch_bounds__(256) void colsum_kernel(const float* __restrict__ W,
    const float* __restrict__ g, const float* __restrict__ bvec,
    const float* __restrict__ bias, float* __restrict__ C1, float* __restrict__ CB,
    int K, int N)
{
  __shared__ float red[2][256];
  const int col = blockIdx.x * 64 + (threadIdx.x & 63);
  const int ks  = threadIdx.x >> 6;
  const int kq  = K >> 2;
  float a1 = 0.f, a2 = 0.f;
  for (int k = ks * kq; k < (ks + 1) * kq; ++k) {
    const float wv = W[(size_t)k * N + col];
    a1 += g[k] * wv;
    a2 += bvec[k] * wv;
  }
  red[0][threadIdx.x] = a1;
  red[1][threadIdx.x] = a2;
  __syncthreads();
  if (threadIdx.x < 64) {
    float s1 = 0.f, s2 = 0.f;
    #pragma unroll
    for (int i = 0; i < 4; ++i) { s1 += red[0][threadIdx.x + i * 64]; s2 += red[1][threadIdx.x + i * 64]; }
    const float sc = (S && col < 256) ? SCALEF : 1.0f;
    C1[col] = sc * s1;
    CB[col] = sc * (s2 + bias[col]);
  }
}

// ------------- Kernel 4: padded rel-pos bias table Bias[8][64][64] f32 ----------
__global__ __launch_bounds__(256) void biasgen_kernel(const float* __restrict__ rpb,
    float* __restrict__ biasT)
{
  const int i = blockIdx.x * 256 + threadIdx.x;
  const int h = i >> 12, n = (i >> 6) & 63, m = i & 63;
  float v;
  if (m >= 49) {
    v = -1e30f;
  } else {
    const int nc = n < 49 ? n : 48;
    const int dI = nc / 7 - m / 7 + 6;
    const int dJ = nc % 7 - m % 7 + 6;
    v = rpb[(dI * 13 + dJ) * 8 + h];
  }
  biasT[i] = v;
}

// ------------- MFMA bf16 GEMM, 128x128 tile, XCD-aware 1D grid -----------------
// LDS k-slot XOR swizzle (T2, rule #21): linear gload_lds dest + inverse-swizzled
// SOURCE + matching XOR on the ds_read slot -> conflict-free ds_read_b128.
// EPI 0: LN1-trick (C1/CB/stats) -> bf16     (QKV)
// EPI 1: +bias +res(bf16) -> bf16            (proj + shortcut)
// EPI 2: +bias, fast GELU (exp2 form) -> bf16 (fc1)
// EPI 4: transposed fc2: A=W[256][1024], Bt=H1; +bias(ch) +res(E) -> f32 NCHW
template<int EPI, int OSW>
__global__ __launch_bounds__(256) void mfma_gemm(
    const unsigned short* __restrict__ A, const unsigned short* __restrict__ Bt,
    const float* __restrict__ bias, const float* __restrict__ C1,
    const float2* __restrict__ stats, const unsigned short* __restrict__ resp,
    void* __restrict__ outp, int K, int N, int row0, int n_outer, int n_inner)
{
  __shared__ unsigned short Asm[128 * 64];
  __shared__ unsigned short Bsm[128 * 64];
  const int tid  = threadIdx.x;
  const int lane = tid & 63;
  const int wid  = tid >> 6;
  const int wr   = wid >> 1;
  const int wc   = wid & 1;

  int outer, inner;
  if ((n_outer & 7) == 0) {
    const int slot = blockIdx.x >> 3;
    outer = (slot / n_inner) * 8 + (blockIdx.x & 7);
    inner = slot - (slot / n_inner) * n_inner;
  } else {
    outer = blockIdx.x / n_inner;
    inner = blockIdx.x - outer * n_inner;
  }
  const int bm = (OSW ? inner : outer) * 128;
  const int bn = (OSW ? outer : inner) * 128;

  f32x4 acc[4][4] = {};

  const int srow = (lane >> 3);
  const int skc  = ((lane & 7) ^ srow) * 8;   // swizzled source k-slot

  for (int k0 = 0; k0 < K; k0 += 64) {
    #pragma unroll
    for (int i = 0; i < 4; ++i) {
      const int ch  = wid * 4 + i;
      const int row = ch * 8 + srow;
      GLOAD_LDS16(A  + (size_t)(bm + row) * K + k0 + skc, &Asm[ch * 512]);
      GLOAD_LDS16(Bt + (size_t)(bn + row) * K + k0 + skc, &Bsm[ch * 512]);
    }
    __syncthreads();

    const int xr = lane & 7;
    const int lg = lane >> 4;
    #pragma unroll
    for (int k32 = 0; k32 < 2; ++k32) {
      const int koff = ((k32 * 4 + lg) ^ xr) * 8;   // swizzled read slot
      bf16x8 af[4], bv[4];
      #pragma unroll
      for (int f = 0; f < 4; ++f) {
        af[f] = *reinterpret_cast<const bf16x8*>(
            &Asm[(wr * 64 + f * 16 + (lane & 15)) * 64 + koff]);
        bv[f] = *reinterpret_cast<const bf16x8*>(
            &Bsm[(wc * 64 + f * 16 + (lane & 15)) * 64 + koff]);
      }
      #pragma unroll
      for (int fm = 0; fm < 4; ++fm)
        #pragma unroll
        for (int fn = 0; fn < 4; ++fn)
          acc[fm][fn] = __builtin_amdgcn_mfma_f32_16x16x32_bf16(
              af[fm], bv[fn], acc[fm][fn], 0, 0, 0);
    }
    __syncthreads();
  }

  const int lr4 = (lane >> 4) * 4;
  const int lc  = lane & 15;
  if constexpr (EPI == 0) {
    float rsv[4][4], rmv[4][4];
    #pragma unroll
    for (int fm = 0; fm < 4; ++fm)
      #pragma unroll
      for (int r = 0; r < 4; ++r) {
        const float2 st = stats[bm + wr * 64 + fm * 16 + lr4 + r];
        rsv[fm][r] = st.y;
        rmv[fm][r] = -st.y * st.x;
      }
    #pragma unroll
    for (int fn = 0; fn < 4; ++fn) {
      const int gcol = bn + wc * 64 + fn * 16 + lc;
      const float c1 = C1[gcol], cb = bias[gcol];
      #pragma unroll
      for (int fm = 0; fm < 4; ++fm)
        #pragma unroll
        for (int r = 0; r < 4; ++r) {
          const int grow = bm + wr * 64 + fm * 16 + lr4 + r;
          const float v = rsv[fm][r] * acc[fm][fn][r] + rmv[fm][r] * c1 + cb;
          ((unsigned short*)outp)[(size_t)grow * N + gcol] = f2bf(v);
        }
    }
  } else if constexpr (EPI == 4) {
    float bch[4][4];
    #pragma unroll
    for (int fm = 0; fm < 4; ++fm)
      #pragma unroll
      for (int r = 0; r < 4; ++r)
        bch[fm][r] = bias[bm + wr * 64 + fm * 16 + lr4 + r];
    #pragma unroll
    for (int fn = 0; fn < 4; ++fn) {
      const int gtok = bn + wc * 64 + fn * 16 + lc;
      const int mg = row0 + gtok;
      const int b  = mg / HW;
      const int sp = mg - b * HW;
      float* ob = (float*)outp + (size_t)b * 256 * HW + sp;
      #pragma unroll
      for (int fm = 0; fm < 4; ++fm) {
        const int ch0 = bm + wr * 64 + fm * 16 + lr4;
        const ushort4 r4 = *reinterpret_cast<const ushort4*>(
            &resp[(size_t)gtok * 256 + ch0]);
        const float rr[4] = {bf2f(r4.x), bf2f(r4.y), bf2f(r4.z), bf2f(r4.w)};
        #pragma unroll
        for (int r = 0; r < 4; ++r)
          ob[(size_t)(ch0 + r) * HW] = acc[fm][fn][r] + bch[fm][r] + rr[r];
      }
    }
  } else {
    #pragma unroll
    for (int fn = 0; fn < 4; ++fn) {
      const int gcol = bn + wc * 64 + fn * 16 + lc;
      const float bvs = bias[gcol];
      #pragma unroll
      for (int fm = 0; fm < 4; ++fm) {
        #pragma unroll
        for (int r = 0; r < 4; ++r) {
          const int grow = bm + wr * 64 + fm * 16 + lr4 + r;
          float v = acc[fm][fn][r] + bvs;
          if constexpr (EPI == 1) {
            v += bf2f(resp[(size_t)grow * 256 + gcol]);
            ((unsigned short*)outp)[(size_t)grow * N + gcol] = f2bf(v);
          } else {
            // fast GELU, exp2 form: 1.5957691*log2(e) folded -> one fewer v_mul
            const float z2 = 2.3022161f * (v + 0.044715f * v * v * v);
            v = v / (1.0f + exp2f(-z2));
            ((unsigned short*)outp)[(size_t)grow * N + gcol] = f2bf(v);
          }
        }
      }
    }
  }
}

// ------------- Kernel 5: MFMA windowed attention, one block per window ----------
__global__ __launch_bounds__(256) void attn_mfma(const unsigned short* __restrict__ qkv,
    const float* __restrict__ biasT, unsigned short* __restrict__ outD)
{
  __shared__ char smem[4 * 14848];
  const int tid  = threadIdx.x;
  const int lane = tid & 63;
  const int wid  = tid >> 6;
  char* base = smem + wid * 14848;
  char* Qs = base;
  char* Ks = base + 5120;
  char* Vt = base + 10240;
  char* Ps = base;

  const int blk = blockIdx.x;
  const int b   = blk >> 6;
  const int di  = (blk >> 3) & 7;
  const int dj  = blk & 7;
  const size_t t00 = (size_t)b * HW + di * Ww + dj;

  const int lg = lane >> 4;
  const int lc = lane & 15;

  for (int rep = 0; rep < 2; ++rep) {
    const int h = wid * 2 + rep;

    for (int i = lane; i < 300; i += 64) {
      if (i < 150) reinterpret_cast<unsigned long long*>(Qs + 49 * 80)[i] = 0ull;
      else         reinterpret_cast<unsigned long long*>(Ks + 49 * 80)[i - 150] = 0ull;
    }
    for (int i = lane; i < 192; i += 64) {
      const int row = i / 6, q = i - (i / 6) * 6;
      *reinterpret_cast<unsigned long long*>(Vt + row * 144 + 96 + q * 8) = 0ull;
    }

    for (int idx = lane; idx < 392; idx += 64) {
      const int row = idx >> 3, dq = idx & 7;
      const int li = row / 7, lj = row - (row / 7) * 7;
      const size_t t = t00 + (size_t)(li * 8) * Ww + lj * 8;
      const unsigned short* src = qkv + t * 768 + h * 32 + dq * 4;
      *reinterpret_cast<uint2*>(Qs + row * 80 + dq * 8) =
          *reinterpret_cast<const uint2*>(src);
      *reinterpret_cast<uint2*>(Ks + row * 80 + dq * 8) =
          *reinterpret_cast<const uint2*>(src + 256);
    }
    for (int idx = lane; idx < 784; idx += 64) {
      const int row = idx >> 4, q = idx & 15;
      const int li = row / 7, lj = row - (row / 7) * 7;
      const size_t t = t00 + (size_t)(li * 8) * Ww + lj * 8;
      const unsigned int v = *reinterpret_cast<const unsigned int*>(
          qkv + t * 768 + h * 32 + 512 + q * 2);
      *reinterpret_cast<unsigned short*>(Vt + (2 * q) * 144 + row * 2) =
          (unsigned short)(v & 0xffff);
      *reinterpret_cast<unsigned short*>(Vt + (2 * q + 1) * 144 + row * 2) =
          (unsigned short)(v >> 16);
    }

    f32x4 sacc[4][4] = {};
    {
      bf16x8 af[4], bv[4];
      #pragma unroll
      for (int f = 0; f < 4; ++f) {
        af[f] = *reinterpret_cast<const bf16x8*>(Qs + (f * 16 + lc) * 80 + lg * 16);
        bv[f] = *reinterpret_cast<const bf16x8*>(Ks + (f * 16 + lc) * 80 + lg * 16);
      }
      #pragma unroll
      for (int fm = 0; fm < 4; ++fm)
        #pragma unroll
        for (int fn = 0; fn < 4; ++fn)
          sacc[fm][fn] = __builtin_amdgcn_mfma_f32_16x16x32_bf16(
              af[fm], bv[fn], sacc[fm][fn], 0, 0, 0);
    }

    const float* bh = biasT + h * 4096;
    #pragma unroll
    for (int fm = 0; fm < 4; ++fm) {
      float rowv[4][4];
      #pragma unroll
      for (int r = 0; r < 4; ++r) {
        const int n = fm * 16 + lg * 4 + r;
        #pragma unroll
        for (int fn = 0; fn < 4; ++fn)
          rowv[r][fn] = sacc[fm][fn][r] + bh[n * 64 + fn * 16 + lc];
      }
      #pragma unroll
      for (int r = 0; r < 4; ++r) {
        float mx = fmaxf(fmaxf(rowv[r][0], rowv[r][1]), fmaxf(rowv[r][2], rowv[r][3]));
        #pragma unroll
        for (int o = 8; o >= 1; o >>= 1) mx = fmaxf(mx, __shfl_xor(mx, o));
        float p[4], sm = 0.f;
        #pragma unroll
        for (int fn = 0; fn < 4; ++fn) { p[fn] = __expf(rowv[r][fn] - mx); sm += p[fn]; }
        #pragma unroll
        for (int o = 8; o >= 1; o >>= 1) sm += __shfl_xor(sm, o);
        const float inv = 1.0f / sm;
        const int n = fm * 16 + lg * 4 + r;
        #pragma unroll
        for (int fn = 0; fn < 4; ++fn)
          *reinterpret_cast<unsigned short*>(Ps + n * 144 + (fn * 16 + lc) * 2) =
              f2bf(p[fn] * inv);
      }
    }

    f32x4 oacc[4][2] = {};
    #pragma unroll
    for (int ks = 0; ks < 2; ++ks) {
      bf16x8 pa[4], vb[2];
      #pragma unroll
      for (int fm = 0; fm < 4; ++fm)
        pa[fm] = *reinterpret_cast<const bf16x8*>(
            Ps + (fm * 16 + lc) * 144 + ks * 64 + lg * 16);
      #pragma unroll
      for (int fn = 0; fn < 2; ++fn)
        vb[fn] = *reinterpret_cast<const bf16x8*>(
            Vt + (fn * 16 + lc) * 144 + ks * 64 + lg * 16);
      #pragma unroll
      for (int fm = 0; fm < 4; ++fm)
        #pragma unroll
        for (int fn = 0; fn < 2; ++fn)
          oacc[fm][fn] = __builtin_amdgcn_mfma_f32_16x16x32_bf16(
              pa[fm], vb[fn], oacc[fm][fn], 0, 0, 0);
    }

    #pragma unroll
    for (int fm = 0; fm < 4; ++fm) {
      #pragma unroll
      for (int r = 0; r < 4; ++r) {
        const int n = fm * 16 + lg * 4 + r;
        if (n < 49) {
          const int li = n / 7, lj = n - (n / 7) * 7;
          const size_t t = t00 + (size_t)(li * 8) * Ww + lj * 8;
          outD[t * 256 + h * 32 + lc]      = f2bf(oacc[fm][0][r]);
          outD[t * 256 + h * 32 + 16 + lc] = f2bf(oacc[fm][1][r]);
        }
      }
    }
  }
}

// ------------------------------- launcher --------------------------------------
extern "C" void kernel_launch(void* const* d_in, const int* in_sizes, int n_in,
                              void* d_out, int out_size, void* d_ws, size_t ws_size,
                              hipStream_t stream) {
  (void)in_sizes; (void)n_in; (void)out_size;
  const float* x      = (const float*)d_in[0];
  const float* cpe_w  = (const float*)d_in[1];
  const float* cpe_b  = (const float*)d_in[2];
  const float* ln1_w  = (const float*)d_in[3];
  const float* ln1_b  = (const float*)d_in[4];
  const float* rpb    = (const float*)d_in[5];
  const float* qkv_w  = (const float*)d_in[6];
  const float* qkv_b  = (const float*)d_in[7];
  const float* proj_w = (const float*)d_in[8];
  const float* proj_b = (const float*)d_in[9];
  const float* ln2_w  = (const float*)d_in[10];
  const float* ln2_b  = (const float*)d_in[11];
  const float* fc1_w  = (const float*)d_in[12];
  const float* fc1_b  = (const float*)d_in[13];
  const float* fc2_w  = (const float*)d_in[14];
  const float* fc2_b  = (const float*)d_in[15];

  char* ws = (char*)d_ws;
  unsigned short* qkv_wt  = (unsigned short*)(ws);
  unsigned short* proj_wt = (unsigned short*)(ws + 393216);
  unsigned short* fc1_wt  = (unsigned short*)(ws + 524288);
  unsigned short* fc2_wt  = (unsigned short*)(ws + 1048576);
  float*  C1q = (float*)(ws + 1572864);
  float*  CBq = (float*)(ws + 1575936);

  int NB_rt;
  if      (ws_size >= 311000000ull) NB_rt = 32;
  else if (ws_size >= 157000000ull) NB_rt = 16;
  else                              NB_rt = 8;
  const int MCHrt = NB_rt * HW;
  const int NCH   = 32 / NB_rt;
  const int NOUT  = MCHrt / 128;

  unsigned short *slotX, *slotQ, *slotE;
  float2* statsFull = nullptr;
  float*  biasTp;
  if (NB_rt == 8) {
    slotX  = (unsigned short*)(ws + 1579008);
    slotQ  = (unsigned short*)(ws + 14424064);
    slotE  = (unsigned short*)(ws + 65804288);
    biasTp = (float*)(ws + 65804288 + 200704);
  } else {
    biasTp    = (float*)(ws + 1579008);
    statsFull = (float2*)(ws + 1710080);
    size_t o = 2512896;
    slotX = (unsigned short*)(ws + o); o += (size_t)MCHrt * 256 * 2;
    slotQ = (unsigned short*)(ws + o); o += (size_t)MCHrt * 1024 * 2;
    slotE = (unsigned short*)(ws + o);
  }

  unsigned short* Araw = (unsigned short*)d_out + 25690112;

  wconv_kernel<1><<<dim3(8, 24), 256, 0, stream>>>(qkv_w,  ln1_w,  qkv_wt,  256, 768);
  wconv_kernel<0><<<dim3(8, 8),  256, 0, stream>>>(proj_w, nullptr, proj_wt, 256, 256);
  wconv_kernel<0><<<dim3(8, 32), 256, 0, stream>>>(fc1_w,  nullptr, fc1_wt,  256, 1024);
  wconv_kernel<0><<<dim3(32, 8), 256, 0, stream>>>(fc2_w,  nullptr, fc2_wt,  1024, 256);
  colsum_kernel<1><<<12, 256, 0, stream>>>(qkv_w, ln1_w, ln1_b, qkv_b, C1q, CBq, 256, 768);

  cpe_kernel<<<32 * 7 * 16, 256, 0, stream>>>(x, cpe_w, cpe_b, Araw);

  if (NB_rt != 8) {
    stats_bf16<<<Tn / 4, 256, 0, stream>>>(Araw, statsFull);
    biasgen_kernel<<<128, 256, 0, stream>>>(rpb, biasTp);
  }

  for (int c = 0; c < NCH; ++c) {
    const int r0 = c * MCHrt;
    const unsigned short* Ac = Araw + (size_t)r0 * Cc;
    const float2* stp;
    if (NB_rt == 8) {
      float2* stloc = (float2*)slotE;
      stats_bf16<<<MCHrt / 4, 256, 0, stream>>>(Ac, stloc);
      biasgen_kernel<<<128, 256, 0, stream>>>(rpb, biasTp);
      stp = stloc;
    } else {
      stp = statsFull + r0;
    }
    // 3. QKV GEMM (LN1 epilogue) -> slotQ
    mfma_gemm<0, 0><<<NOUT * 6, 256, 0, stream>>>(
        Ac, qkv_wt, CBq, C1q, stp, nullptr, slotQ, 256, 768, 0, NOUT, 6);
    // 4. MFMA windowed attention -> D (slotX)
    attn_mfma<<<NB_rt * 64, 256, 0, stream>>>(slotQ, biasTp, slotX);
    // 5. proj GEMM + bias + shortcut(A bf16) -> E (slotE)
    mfma_gemm<1, 0><<<NOUT * 2, 256, 0, stream>>>(
        slotX, proj_wt, proj_b, nullptr, nullptr, Ac, slotE, 256, 256, 0, NOUT, 2);
    // 6. LN2 apply -> bf16 G (slotX)
    ln_apply_bf16<<<MCHrt / 4, 256, 0, stream>>>(slotE, ln2_w, ln2_b, slotX);
    // 7. FC1 + fast GELU -> bf16 H1 (slotQ)
    mfma_gemm<2, 0><<<NOUT * 8, 256, 0, stream>>>(
        slotX, fc1_wt, fc1_b, nullptr, nullptr, nullptr, slotQ, 256, 1024, 0, NOUT, 8);
    // 8. transposed FC2: A=fc2_wt, Bt=H1; +bias(ch) +res(E) -> f32 NCHW out
    mfma_gemm<4, 1><<<NOUT * 2, 256, 0, stream>>>(
        fc2_wt, slotQ, fc2_b, nullptr, nullptr, slotE, d_out, 1024, 256, r0, NOUT, 2);
  }
}

// Round 17
// 658.815 us; speedup vs baseline: 1.0117x; 1.0117x over previous
//
#include <hip/hip_runtime.h>
#include <hip/hip_bf16.h>

#define DEVINL __device__ __forceinline__

constexpr int Cc  = 256;
constexpr int Hh  = 56;
constexpr int Ww  = 56;
constexpr int Tn  = 32 * 56 * 56;   // 100352 tokens
constexpr int HW  = Hh * Ww;        // 3136
constexpr float SCALEF = 0.17677669529663689f;  // 32^-0.5

typedef __attribute__((ext_vector_type(4))) float f32x4;
typedef __attribute__((ext_vector_type(8))) short bf16x8;

DEVINL unsigned short f2bf(float f) {
  __hip_bfloat16 h = __float2bfloat16(f);
  return *reinterpret_cast<unsigned short*>(&h);
}
DEVINL float bf2f(unsigned short u) {
  union { unsigned int i; float f; } v; v.i = (unsigned int)u << 16; return v.f;
}

#define GLOAD_LDS16(gp, lp) \
  __builtin_amdgcn_global_load_lds((const __attribute__((address_space(1))) void*)(gp), \
                                   (__attribute__((address_space(3))) void*)(lp), 16, 0, 0)

// ------------- Kernel 1: depthwise 3x3 CPE + residual -> token(t,c) bf16 --------
// LDS strides 620(ch)/60(row): 8B-aligned rows -> ushort4+ushort2 vector reads.
__global__ __launch_bounds__(256) void cpe_kernel(const float* __restrict__ x,
    const float* __restrict__ cw, const float* __restrict__ cb,
    unsigned short* __restrict__ out)
{
  __shared__ unsigned short Xs[16 * 620];
  const int tid = threadIdx.x;
  const int bx  = blockIdx.x;
  const int cg  = bx & 15;
  const int t2  = bx >> 4;
  const int hg  = t2 % 7;
  const int b   = t2 / 7;
  const int c0  = cg * 16;
  const int h0  = hg * 8;

  for (int idx = tid; idx < 16 * 580; idx += 256) {
    const int ci  = idx / 580;
    const int rem = idx - ci * 580;
    const int rr  = rem / 58;
    const int wc  = rem - rr * 58;
    const int h2  = h0 - 1 + rr;
    const int w2  = wc - 1;
    float v = 0.f;
    if (h2 >= 0 && h2 < Hh && w2 >= 0 && w2 < Ww)
      v = x[((size_t)(b * Cc + c0 + ci)) * HW + h2 * Ww + w2];
    Xs[ci * 620 + rr * 60 + wc] = f2bf(v);
  }
  __syncthreads();

  const int ci = tid & 15;
  const int c  = c0 + ci;
  float wr9[9];
  #pragma unroll
  for (int i = 0; i < 9; ++i) wr9[i] = cw[c * 9 + i];
  const float cbv = cb[c];
  const unsigned short* Xc = Xs + ci * 620;

  #pragma unroll
  for (int it = 0; it < 7; ++it) {
    const int tg   = it * 16 + (tid >> 4);
    const int tok0 = tg * 4;
    const int hr   = tok0 / 56;
    const int w0   = tok0 - hr * 56;
    float rv[3][6];
    #pragma unroll
    for (int j = 0; j < 3; ++j) {
      const ushort4 a = *reinterpret_cast<const ushort4*>(Xc + (hr + j) * 60 + w0);
      const ushort2 e = *reinterpret_cast<const ushort2*>(Xc + (hr + j) * 60 + w0 + 4);
      rv[j][0] = bf2f(a.x); rv[j][1] = bf2f(a.y); rv[j][2] = bf2f(a.z);
      rv[j][3] = bf2f(a.w); rv[j][4] = bf2f(e.x); rv[j][5] = bf2f(e.y);
    }
    unsigned short ov[4];
    #pragma unroll
    for (int t = 0; t < 4; ++t) {
      float acc = rv[1][t + 1];   // residual (center x)
      acc += wr9[0] * rv[0][t] + wr9[1] * rv[0][t + 1] + wr9[2] * rv[0][t + 2];
      acc += wr9[3] * rv[1][t] + wr9[4] * rv[1][t + 1] + wr9[5] * rv[1][t + 2];
      acc += wr9[6] * rv[2][t] + wr9[7] * rv[2][t + 1] + wr9[8] * rv[2][t + 2];
      ov[t] = f2bf(acc + cbv);
    }
    const size_t tbase = (size_t)b * HW + (h0 + hr) * Ww + w0;
    #pragma unroll
    for (int t = 0; t < 4; ++t)
      out[(tbase + t) * Cc + c] = ov[t];
  }
}

// ------------- Kernel 2: per-token LN stats on bf16 rows -> float2{mu, rs} ------
__global__ __launch_bounds__(256) void stats_bf16(const unsigned short* __restrict__ in,
    float2* __restrict__ st)
{
  const int lane = threadIdx.x & 63;
  const size_t t = (size_t)blockIdx.x * 4 + (threadIdx.x >> 6);
  const ushort4 v = *reinterpret_cast<const ushort4*>(in + t * Cc + lane * 4);
  const float v0 = bf2f(v.x), v1 = bf2f(v.y), v2 = bf2f(v.z), v3 = bf2f(v.w);
  float s  = v0 + v1 + v2 + v3;
  float sq = v0 * v0 + v1 * v1 + v2 * v2 + v3 * v3;
  #pragma unroll
  for (int o = 32; o >= 1; o >>= 1) {
    s  += __shfl_xor(s, o);
    sq += __shfl_xor(sq, o);
  }
  if (lane == 0) {
    const float mean = s * (1.0f / Cc);
    const float var  = sq * (1.0f / Cc) - mean * mean;
    st[t] = make_float2(mean, rsqrtf(var + 1e-5f));
  }
}

// ------------- Kernel 2b: fused LN stats+apply, bf16 -> bf16 --------------------
__global__ __launch_bounds__(256) void ln_apply_bf16(const unsigned short* __restrict__ inp,
    const float* __restrict__ w, const float* __restrict__ b,
    unsigned short* __restrict__ out)
{
  const int lane = threadIdx.x & 63;
  const size_t t = (size_t)blockIdx.x * 4 + (threadIdx.x >> 6);
  const ushort4 v = *reinterpret_cast<const ushort4*>(inp + t * Cc + lane * 4);
  const float v0 = bf2f(v.x), v1 = bf2f(v.y), v2 = bf2f(v.z), v3 = bf2f(v.w);
  float s  = v0 + v1 + v2 + v3;
  float sq = v0 * v0 + v1 * v1 + v2 * v2 + v3 * v3;
  #pragma unroll
  for (int o = 32; o >= 1; o >>= 1) {
    s  += __shfl_xor(s, o);
    sq += __shfl_xor(sq, o);
  }
  const float mean = s * (1.0f / Cc);
  const float var  = sq * (1.0f / Cc) - mean * mean;
  const float r    = rsqrtf(var + 1e-5f);
  const float4 w4 = *reinterpret_cast<const float4*>(w + lane * 4);
  const float4 b4 = *reinterpret_cast<const float4*>(b + lane * 4);
  ushort4 o;
  o.x = f2bf((v0 - mean) * r * w4.x + b4.x);
  o.y = f2bf((v1 - mean) * r * w4.y + b4.y);
  o.z = f2bf((v2 - mean) * r * w4.z + b4.z);
  o.w = f2bf((v3 - mean) * r * w4.w + b4.w);
  *reinterpret_cast<ushort4*>(out + t * Cc + lane * 4) = o;
}

// ------------- Kernel 3: weight transpose+fold f32[K][N] -> bf16 Wt[N][K] -------
template<int QS>
__global__ __launch_bounds__(256) void wconv_kernel(const float* __restrict__ W,
    const float* __restrict__ g, unsigned short* __restrict__ Wt, int K, int N)
{
  __shared__ float Xs[32][33];
  const int kb = blockIdx.x * 32, nb = blockIdx.y * 32;
  const int tn = threadIdx.x & 31, tk = threadIdx.x >> 5;
  #pragma unroll
  for (int i = 0; i < 4; ++i) {
    const int k = kb + tk + i * 8;
    const float gv = g ? g[k] : 1.0f;
    Xs[tk + i * 8][tn] = W[(size_t)k * N + nb + tn] * gv;
  }
  __syncthreads();
  const int wk = threadIdx.x & 31, wn = threadIdx.x >> 5;
  #pragma unroll
  for (int i = 0; i < 4; ++i) {
    const int n = nb + wn + i * 8;
    const float s = (QS && n < 256) ? SCALEF : 1.0f;
    Wt[(size_t)n * K + kb + wk] = f2bf(Xs[wk][wn + i * 8] * s);
  }
}

// ------------- Kernel 3b: C1[n]=s*sum_k g_k W,  CB[n]=s*(sum_k b_k W + bias) ----
template<int S>
__global__ __launch_bounds__(256) void colsum_kernel(const float* __restrict__ W,
    const float* __restrict__ g, const float* __restrict__ bvec,
    const float* __restrict__ bias, float* __restrict__ C1, float* __restrict__ CB,
    int K, int N)
{
  __shared__ float red[2][256];
  const int col = blockIdx.x * 64 + (threadIdx.x & 63);
  const int ks  = threadIdx.x >> 6;
  const int kq  = K >> 2;
  float a1 = 0.f, a2 = 0.f;
  for (int k = ks * kq; k < (ks + 1) * kq; ++k) {
    const float wv = W[(size_t)k * N + col];
    a1 += g[k] * wv;
    a2 += bvec[k] * wv;
  }
  red[0][threadIdx.x] = a1;
  red[1][threadIdx.x] = a2;
  __syncthreads();
  if (threadIdx.x < 64) {
    float s1 = 0.f, s2 = 0.f;
    #pragma unroll
    for (int i = 0; i < 4; ++i) { s1 += red[0][threadIdx.x + i * 64]; s2 += red[1][threadIdx.x + i * 64]; }
    const float sc = (S && col < 256) ? SCALEF : 1.0f;
    C1[col] = sc * s1;
    CB[col] = sc * (s2 + bias[col]);
  }
}

// ------------- Kernel 4: padded rel-pos bias table Bias[8][64][64] f32 ----------
__global__ __launch_bounds__(256) void biasgen_kernel(const float* __restrict__ rpb,
    float* __restrict__ biasT)
{
  const int i = blockIdx.x * 256 + threadIdx.x;
  const int h = i >> 12, n = (i >> 6) & 63, m = i & 63;
  float v;
  if (m >= 49) {
    v = -1e30f;
  } else {
    const int nc = n < 49 ? n : 48;
    const int dI = nc / 7 - m / 7 + 6;
    const int dJ = nc % 7 - m % 7 + 6;
    v = rpb[(dI * 13 + dJ) * 8 + h];
  }
  biasT[i] = v;
}

// ------------- MFMA bf16 GEMM, 128x128 tile, XCD-aware 1D grid -----------------
// LDS k-slot XOR swizzle (T2, rule #21): linear gload_lds dest + inverse-swizzled
// SOURCE + matching XOR on the ds_read slot -> conflict-free ds_read_b128.
// EPI 0: LN1-trick (C1/CB/stats) -> bf16     (QKV)
// EPI 1: +bias +res(bf16) -> bf16            (proj + shortcut)
// EPI 2: +bias, fast GELU -> bf16            (fc1)
// EPI 4: transposed fc2: A=W[256][1024], Bt=H1; +bias(ch) +res(E) -> f32 NCHW
template<int EPI, int OSW>
__global__ __launch_bounds__(256) void mfma_gemm(
    const unsigned short* __restrict__ A, const unsigned short* __restrict__ Bt,
    const float* __restrict__ bias, const float* __restrict__ C1,
    const float2* __restrict__ stats, const unsigned short* __restrict__ resp,
    void* __restrict__ outp, int K, int N, int row0, int n_outer, int n_inner)
{
  __shared__ unsigned short Asm[128 * 64];
  __shared__ unsigned short Bsm[128 * 64];
  const int tid  = threadIdx.x;
  const int lane = tid & 63;
  const int wid  = tid >> 6;
  const int wr   = wid >> 1;
  const int wc   = wid & 1;

  int outer, inner;
  if ((n_outer & 7) == 0) {
    const int slot = blockIdx.x >> 3;
    outer = (slot / n_inner) * 8 + (blockIdx.x & 7);
    inner = slot - (slot / n_inner) * n_inner;
  } else {
    outer = blockIdx.x / n_inner;
    inner = blockIdx.x - outer * n_inner;
  }
  const int bm = (OSW ? inner : outer) * 128;
  const int bn = (OSW ? outer : inner) * 128;

  f32x4 acc[4][4] = {};

  const int srow = (lane >> 3);
  const int skc  = ((lane & 7) ^ srow) * 8;   // swizzled source k-slot

  for (int k0 = 0; k0 < K; k0 += 64) {
    #pragma unroll
    for (int i = 0; i < 4; ++i) {
      const int ch  = wid * 4 + i;
      const int row = ch * 8 + srow;
      GLOAD_LDS16(A  + (size_t)(bm + row) * K + k0 + skc, &Asm[ch * 512]);
      GLOAD_LDS16(Bt + (size_t)(bn + row) * K + k0 + skc, &Bsm[ch * 512]);
    }
    __syncthreads();

    const int xr = lane & 7;
    const int lg = lane >> 4;
    #pragma unroll
    for (int k32 = 0; k32 < 2; ++k32) {
      const int koff = ((k32 * 4 + lg) ^ xr) * 8;   // swizzled read slot
      bf16x8 af[4], bv[4];
      #pragma unroll
      for (int f = 0; f < 4; ++f) {
        af[f] = *reinterpret_cast<const bf16x8*>(
            &Asm[(wr * 64 + f * 16 + (lane & 15)) * 64 + koff]);
        bv[f] = *reinterpret_cast<const bf16x8*>(
            &Bsm[(wc * 64 + f * 16 + (lane & 15)) * 64 + koff]);
      }
      #pragma unroll
      for (int fm = 0; fm < 4; ++fm)
        #pragma unroll
        for (int fn = 0; fn < 4; ++fn)
          acc[fm][fn] = __builtin_amdgcn_mfma_f32_16x16x32_bf16(
              af[fm], bv[fn], acc[fm][fn], 0, 0, 0);
    }
    __syncthreads();
  }

  const int lr4 = (lane >> 4) * 4;
  const int lc  = lane & 15;
  if constexpr (EPI == 0) {
    float rsv[4][4], rmv[4][4];
    #pragma unroll
    for (int fm = 0; fm < 4; ++fm)
      #pragma unroll
      for (int r = 0; r < 4; ++r) {
        const float2 st = stats[bm + wr * 64 + fm * 16 + lr4 + r];
        rsv[fm][r] = st.y;
        rmv[fm][r] = -st.y * st.x;
      }
    #pragma unroll
    for (int fn = 0; fn < 4; ++fn) {
      const int gcol = bn + wc * 64 + fn * 16 + lc;
      const float c1 = C1[gcol], cb = bias[gcol];
      #pragma unroll
      for (int fm = 0; fm < 4; ++fm)
        #pragma unroll
        for (int r = 0; r < 4; ++r) {
          const int grow = bm + wr * 64 + fm * 16 + lr4 + r;
          const float v = rsv[fm][r] * acc[fm][fn][r] + rmv[fm][r] * c1 + cb;
          ((unsigned short*)outp)[(size_t)grow * N + gcol] = f2bf(v);
        }
    }
  } else if constexpr (EPI == 4) {
    float bch[4][4];
    #pragma unroll
    for (int fm = 0; fm < 4; ++fm)
      #pragma unroll
      for (int r = 0; r < 4; ++r)
        bch[fm][r] = bias[bm + wr * 64 + fm * 16 + lr4 + r];
    #pragma unroll
    for (int fn = 0; fn < 4; ++fn) {
      const int gtok = bn + wc * 64 + fn * 16 + lc;
      const int mg = row0 + gtok;
      const int b  = mg / HW;
      const int sp = mg - b * HW;
      float* ob = (float*)outp + (size_t)b * 256 * HW + sp;
      #pragma unroll
      for (int fm = 0; fm < 4; ++fm)
        #pragma unroll
        for (int r = 0; r < 4; ++r) {
          const int ch = bm + wr * 64 + fm * 16 + lr4 + r;
          float v = acc[fm][fn][r] + bch[fm][r];
          v += bf2f(resp[(size_t)gtok * 256 + ch]);
          ob[(size_t)ch * HW] = v;
        }
    }
  } else {
    #pragma unroll
    for (int fn = 0; fn < 4; ++fn) {
      const int gcol = bn + wc * 64 + fn * 16 + lc;
      const float bvs = bias[gcol];
      #pragma unroll
      for (int fm = 0; fm < 4; ++fm) {
        #pragma unroll
        for (int r = 0; r < 4; ++r) {
          const int grow = bm + wr * 64 + fm * 16 + lr4 + r;
          float v = acc[fm][fn][r] + bvs;
          if constexpr (EPI == 1) {
            v += bf2f(resp[(size_t)grow * 256 + gcol]);
            ((unsigned short*)outp)[(size_t)grow * N + gcol] = f2bf(v);
          } else {
            // fast GELU: v * sigmoid(1.5957691*(v + 0.044715 v^3))
            const float z = 1.5957691f * (v + 0.044715f * v * v * v);
            v = v / (1.0f + __expf(-z));
            ((unsigned short*)outp)[(size_t)grow * N + gcol] = f2bf(v);
          }
        }
      }
    }
  }
}

// ------------- Kernel 5: MFMA windowed attention, one block per window ----------
__global__ __launch_bounds__(256) void attn_mfma(const unsigned short* __restrict__ qkv,
    const float* __restrict__ biasT, unsigned short* __restrict__ outD)
{
  __shared__ char smem[4 * 14848];
  const int tid  = threadIdx.x;
  const int lane = tid & 63;
  const int wid  = tid >> 6;
  char* base = smem + wid * 14848;
  char* Qs = base;
  char* Ks = base + 5120;
  char* Vt = base + 10240;
  char* Ps = base;

  const int blk = blockIdx.x;
  const int b   = blk >> 6;
  const int di  = (blk >> 3) & 7;
  const int dj  = blk & 7;
  const size_t t00 = (size_t)b * HW + di * Ww + dj;

  const int lg = lane >> 4;
  const int lc = lane & 15;

  for (int rep = 0; rep < 2; ++rep) {
    const int h = wid * 2 + rep;

    for (int i = lane; i < 300; i += 64) {
      if (i < 150) reinterpret_cast<unsigned long long*>(Qs + 49 * 80)[i] = 0ull;
      else         reinterpret_cast<unsigned long long*>(Ks + 49 * 80)[i - 150] = 0ull;
    }
    for (int i = lane; i < 192; i += 64) {
      const int row = i / 6, q = i - (i / 6) * 6;
      *reinterpret_cast<unsigned long long*>(Vt + row * 144 + 96 + q * 8) = 0ull;
    }

    for (int idx = lane; idx < 392; idx += 64) {
      const int row = idx >> 3, dq = idx & 7;
      const int li = row / 7, lj = row - (row / 7) * 7;
      const size_t t = t00 + (size_t)(li * 8) * Ww + lj * 8;
      const unsigned short* src = qkv + t * 768 + h * 32 + dq * 4;
      *reinterpret_cast<uint2*>(Qs + row * 80 + dq * 8) =
          *reinterpret_cast<const uint2*>(src);
      *reinterpret_cast<uint2*>(Ks + row * 80 + dq * 8) =
          *reinterpret_cast<const uint2*>(src + 256);
    }
    for (int idx = lane; idx < 784; idx += 64) {
      const int row = idx >> 4, q = idx & 15;
      const int li = row / 7, lj = row - (row / 7) * 7;
      const size_t t = t00 + (size_t)(li * 8) * Ww + lj * 8;
      const unsigned int v = *reinterpret_cast<const unsigned int*>(
          qkv + t * 768 + h * 32 + 512 + q * 2);
      *reinterpret_cast<unsigned short*>(Vt + (2 * q) * 144 + row * 2) =
          (unsigned short)(v & 0xffff);
      *reinterpret_cast<unsigned short*>(Vt + (2 * q + 1) * 144 + row * 2) =
          (unsigned short)(v >> 16);
    }

    f32x4 sacc[4][4] = {};
    {
      bf16x8 af[4], bv[4];
      #pragma unroll
      for (int f = 0; f < 4; ++f) {
        af[f] = *reinterpret_cast<const bf16x8*>(Qs + (f * 16 + lc) * 80 + lg * 16);
        bv[f] = *reinterpret_cast<const bf16x8*>(Ks + (f * 16 + lc) * 80 + lg * 16);
      }
      #pragma unroll
      for (int fm = 0; fm < 4; ++fm)
        #pragma unroll
        for (int fn = 0; fn < 4; ++fn)
          sacc[fm][fn] = __builtin_amdgcn_mfma_f32_16x16x32_bf16(
              af[fm], bv[fn], sacc[fm][fn], 0, 0, 0);
    }

    const float* bh = biasT + h * 4096;
    #pragma unroll
    for (int fm = 0; fm < 4; ++fm) {
      float rowv[4][4];
      #pragma unroll
      for (int r = 0; r < 4; ++r) {
        const int n = fm * 16 + lg * 4 + r;
        #pragma unroll
        for (int fn = 0; fn < 4; ++fn)
          rowv[r][fn] = sacc[fm][fn][r] + bh[n * 64 + fn * 16 + lc];
      }
      #pragma unroll
      for (int r = 0; r < 4; ++r) {
        float mx = fmaxf(fmaxf(rowv[r][0], rowv[r][1]), fmaxf(rowv[r][2], rowv[r][3]));
        #pragma unroll
        for (int o = 8; o >= 1; o >>= 1) mx = fmaxf(mx, __shfl_xor(mx, o));
        float p[4], sm = 0.f;
        #pragma unroll
        for (int fn = 0; fn < 4; ++fn) { p[fn] = __expf(rowv[r][fn] - mx); sm += p[fn]; }
        #pragma unroll
        for (int o = 8; o >= 1; o >>= 1) sm += __shfl_xor(sm, o);
        const float inv = 1.0f / sm;
        const int n = fm * 16 + lg * 4 + r;
        #pragma unroll
        for (int fn = 0; fn < 4; ++fn)
          *reinterpret_cast<unsigned short*>(Ps + n * 144 + (fn * 16 + lc) * 2) =
              f2bf(p[fn] * inv);
      }
    }

    f32x4 oacc[4][2] = {};
    #pragma unroll
    for (int ks = 0; ks < 2; ++ks) {
      bf16x8 pa[4], vb[2];
      #pragma unroll
      for (int fm = 0; fm < 4; ++fm)
        pa[fm] = *reinterpret_cast<const bf16x8*>(
            Ps + (fm * 16 + lc) * 144 + ks * 64 + lg * 16);
      #pragma unroll
      for (int fn = 0; fn < 2; ++fn)
        vb[fn] = *reinterpret_cast<const bf16x8*>(
            Vt + (fn * 16 + lc) * 144 + ks * 64 + lg * 16);
      #pragma unroll
      for (int fm = 0; fm < 4; ++fm)
        #pragma unroll
        for (int fn = 0; fn < 2; ++fn)
          oacc[fm][fn] = __builtin_amdgcn_mfma_f32_16x16x32_bf16(
              pa[fm], vb[fn], oacc[fm][fn], 0, 0, 0);
    }

    #pragma unroll
    for (int fm = 0; fm < 4; ++fm) {
      #pragma unroll
      for (int r = 0; r < 4; ++r) {
        const int n = fm * 16 + lg * 4 + r;
        if (n < 49) {
          const int li = n / 7, lj = n - (n / 7) * 7;
          const size_t t = t00 + (size_t)(li * 8) * Ww + lj * 8;
          outD[t * 256 + h * 32 + lc]      = f2bf(oacc[fm][0][r]);
          outD[t * 256 + h * 32 + 16 + lc] = f2bf(oacc[fm][1][r]);
        }
      }
    }
  }
}

// ------------------------------- launcher --------------------------------------
extern "C" void kernel_launch(void* const* d_in, const int* in_sizes, int n_in,
                              void* d_out, int out_size, void* d_ws, size_t ws_size,
                              hipStream_t stream) {
  (void)in_sizes; (void)n_in; (void)out_size;
  const float* x      = (const float*)d_in[0];
  const float* cpe_w  = (const float*)d_in[1];
  const float* cpe_b  = (const float*)d_in[2];
  const float* ln1_w  = (const float*)d_in[3];
  const float* ln1_b  = (const float*)d_in[4];
  const float* rpb    = (const float*)d_in[5];
  const float* qkv_w  = (const float*)d_in[6];
  const float* qkv_b  = (const float*)d_in[7];
  const float* proj_w = (const float*)d_in[8];
  const float* proj_b = (const float*)d_in[9];
  const float* ln2_w  = (const float*)d_in[10];
  const float* ln2_b  = (const float*)d_in[11];
  const float* fc1_w  = (const float*)d_in[12];
  const float* fc1_b  = (const float*)d_in[13];
  const float* fc2_w  = (const float*)d_in[14];
  const float* fc2_b  = (const float*)d_in[15];

  char* ws = (char*)d_ws;
  unsigned short* qkv_wt  = (unsigned short*)(ws);
  unsigned short* proj_wt = (unsigned short*)(ws + 393216);
  unsigned short* fc1_wt  = (unsigned short*)(ws + 524288);
  unsigned short* fc2_wt  = (unsigned short*)(ws + 1048576);
  float*  C1q = (float*)(ws + 1572864);
  float*  CBq = (float*)(ws + 1575936);

  int NB_rt;
  if      (ws_size >= 311000000ull) NB_rt = 32;
  else if (ws_size >= 157000000ull) NB_rt = 16;
  else                              NB_rt = 8;
  const int MCHrt = NB_rt * HW;
  const int NCH   = 32 / NB_rt;
  const int NOUT  = MCHrt / 128;

  unsigned short *slotX, *slotQ, *slotE;
  float2* statsFull = nullptr;
  float*  biasTp;
  if (NB_rt == 8) {
    slotX  = (unsigned short*)(ws + 1579008);
    slotQ  = (unsigned short*)(ws + 14424064);
    slotE  = (unsigned short*)(ws + 65804288);
    biasTp = (float*)(ws + 65804288 + 200704);
  } else {
    biasTp    = (float*)(ws + 1579008);
    statsFull = (float2*)(ws + 1710080);
    size_t o = 2512896;
    slotX = (unsigned short*)(ws + o); o += (size_t)MCHrt * 256 * 2;
    slotQ = (unsigned short*)(ws + o); o += (size_t)MCHrt * 1024 * 2;
    slotE = (unsigned short*)(ws + o);
  }

  unsigned short* Araw = (unsigned short*)d_out + 25690112;

  wconv_kernel<1><<<dim3(8, 24), 256, 0, stream>>>(qkv_w,  ln1_w,  qkv_wt,  256, 768);
  wconv_kernel<0><<<dim3(8, 8),  256, 0, stream>>>(proj_w, nullptr, proj_wt, 256, 256);
  wconv_kernel<0><<<dim3(8, 32), 256, 0, stream>>>(fc1_w,  nullptr, fc1_wt,  256, 1024);
  wconv_kernel<0><<<dim3(32, 8), 256, 0, stream>>>(fc2_w,  nullptr, fc2_wt,  1024, 256);
  colsum_kernel<1><<<12, 256, 0, stream>>>(qkv_w, ln1_w, ln1_b, qkv_b, C1q, CBq, 256, 768);

  cpe_kernel<<<32 * 7 * 16, 256, 0, stream>>>(x, cpe_w, cpe_b, Araw);

  if (NB_rt != 8) {
    stats_bf16<<<Tn / 4, 256, 0, stream>>>(Araw, statsFull);
    biasgen_kernel<<<128, 256, 0, stream>>>(rpb, biasTp);
  }

  for (int c = 0; c < NCH; ++c) {
    const int r0 = c * MCHrt;
    const unsigned short* Ac = Araw + (size_t)r0 * Cc;
    const float2* stp;
    if (NB_rt == 8) {
      float2* stloc = (float2*)slotE;
      stats_bf16<<<MCHrt / 4, 256, 0, stream>>>(Ac, stloc);
      biasgen_kernel<<<128, 256, 0, stream>>>(rpb, biasTp);
      stp = stloc;
    } else {
      stp = statsFull + r0;
    }
    // 3. QKV GEMM (LN1 epilogue) -> slotQ
    mfma_gemm<0, 0><<<NOUT * 6, 256, 0, stream>>>(
        Ac, qkv_wt, CBq, C1q, stp, nullptr, slotQ, 256, 768, 0, NOUT, 6);
    // 4. MFMA windowed attention -> D (slotX)
    attn_mfma<<<NB_rt * 64, 256, 0, stream>>>(slotQ, biasTp, slotX);
    // 5. proj GEMM + bias + shortcut(A bf16) -> E (slotE)
    mfma_gemm<1, 0><<<NOUT * 2, 256, 0, stream>>>(
        slotX, proj_wt, proj_b, nullptr, nullptr, Ac, slotE, 256, 256, 0, NOUT, 2);
    // 6. LN2 apply -> bf16 G (slotX)
    ln_apply_bf16<<<MCHrt / 4, 256, 0, stream>>>(slotE, ln2_w, ln2_b, slotX);
    // 7. FC1 + fast GELU -> bf16 H1 (slotQ)
    mfma_gemm<2, 0><<<NOUT * 8, 256, 0, stream>>>(
        slotX, fc1_wt, fc1_b, nullptr, nullptr, nullptr, slotQ, 256, 1024, 0, NOUT, 8);
    // 8. transposed FC2: A=fc2_wt, Bt=H1; +bias(ch) +res(E) -> f32 NCHW out
    mfma_gemm<4, 1><<<NOUT * 2, 256, 0, stream>>>(
        fc2_wt, slotQ, fc2_b, nullptr, nullptr, slotE, d_out, 1024, 256, r0, NOUT, 2);
  }
}